// Round 1
// baseline (75647.699 us; speedup 1.0000x reference)
//
#include <hip/hip_runtime.h>
#include <math.h>

#define Hh   512
#define TH   1536
#define LINN 128
#define NWG  64
#define NTH  256
#define JPW  (Hh / NWG)   /* 8 h-indices per WG  */
#define ROWS (3 * JPW)    /* 24 weight rows per WG */

#define WS_A      0
#define WS_CC     6144
#define WS_CH0    12288
#define WS_CH1    14336
#define WS_CRES   16384
#define WS_FLAGS1 18432
#define WS_FLAGS3 18944
#define WS_H1PP   20480
#define WS_HIST   32768

__device__ __forceinline__ float sigm(float v) { return 1.f / (1.f + __expf(-v)); }
__device__ __forceinline__ float tanh_fast(float x) { return 2.f / (1.f + __expf(-2.f * x)) - 1.f; }

// ---------------------------------------------------------------- prep:
// A[row] = W_ih0[row,:] @ W_proc ; CC[row] = W_ih0[row,:] @ b_proc + b_ih0 (+ b_hh0 for r,z rows)
__global__ void prep(const float* __restrict__ Wih0, const float* __restrict__ Wproc,
                     const float* __restrict__ bproc, const float* __restrict__ bih0,
                     const float* __restrict__ bhh0, float* __restrict__ A,
                     float* __restrict__ CC)
{
    int row = blockIdx.x * 256 + threadIdx.x;
    if (row >= TH) return;
    const float* w = Wih0 + (size_t)row * LINN;
    float a = 0.f, c = 0.f;
    for (int k = 0; k < LINN; ++k) { float wv = w[k]; a = fmaf(wv, Wproc[k], a); c = fmaf(wv, bproc[k], c); }
    c += bih0[row];
    if (row < 2 * Hh) c += bhh0[row];
    A[row] = a; CC[row] = c;
}

// ---------------------------------------------------------------- phase1: cell-0 serial scan
__launch_bounds__(NTH, 1)
__global__ void phase1(const float* __restrict__ input, const float* __restrict__ mem0,
                       const float* __restrict__ Whh0, const float* __restrict__ bhh0,
                       const float* __restrict__ A, const float* __restrict__ CC,
                       float* __restrict__ hist, float* __restrict__ carry,
                       float* __restrict__ outp, unsigned* __restrict__ flags,
                       int t0, int tc, int first, int last)
{
    __shared__ __align__(16) float Wl[ROWS * Hh];   // 48 KB weight slice
    __shared__ __align__(16) float hl[Hh];
    const int tid = threadIdx.x;
    const int wg  = blockIdx.x;
    const int jl  = tid >> 5;        // 0..7   local h-index
    const int s   = tid & 31;        // 0..31  k-stripe lane
    const int jg  = wg * JPW + jl;   // global h-index

    for (int i = tid; i < ROWS * Hh; i += NTH) {
        int lr = i >> 9, k = i & (Hh - 1);
        int g = lr % 3, j = lr / 3;
        int grow = g * Hh + wg * JPW + j;
        Wl[i] = Whh0[(size_t)grow * Hh + k];
    }
    {
        const float* src = first ? mem0 : carry;
        hl[tid] = src[tid];
        hl[tid + NTH] = src[tid + NTH];
    }
    const float Ar = A[jg], Az = A[jg + Hh], An = A[jg + 2 * Hh];
    const float Cr = CC[jg], Cz = CC[jg + Hh], Cn = CC[jg + 2 * Hh];
    const float Bn = bhh0[jg + 2 * Hh];
    const float* Wr = &Wl[(jl * 3 + 0) * Hh];
    const float* Wz = &Wl[(jl * 3 + 1) * Hh];
    const float* Wn = &Wl[(jl * 3 + 2) * Hh];
    __syncthreads();

    for (int t = 0; t < tc; ++t) {
        const float x = input[t0 + t];
        float ar = 0.f, az = 0.f, an = 0.f;
#pragma unroll
        for (int i = 0; i < Hh / 32; ++i) {
            const int k = s + 32 * i;
            const float hk = hl[k];
            ar = fmaf(Wr[k], hk, ar);
            az = fmaf(Wz[k], hk, az);
            an = fmaf(Wn[k], hk, an);
        }
#pragma unroll
        for (int o = 16; o > 0; o >>= 1) {
            ar += __shfl_xor(ar, o);
            az += __shfl_xor(az, o);
            an += __shfl_xor(an, o);
        }
        if (s == 0) {
            const float r  = sigm(fmaf(Ar, x, Cr) + ar);
            const float z  = sigm(fmaf(Az, x, Cz) + az);
            const float n  = tanh_fast(fmaf(An, x, Cn) + r * (an + Bn));
            const float hn = (1.f - z) * n + z * hl[jg];
            __hip_atomic_store(&hist[(size_t)t * Hh + jg], hn,
                               __ATOMIC_RELAXED, __HIP_MEMORY_SCOPE_AGENT);
        }
        __syncthreads();                     // all slice stores drained (vmcnt before barrier)
        if (tid == 0)
            __hip_atomic_store(&flags[wg], (unsigned)(t0 + t + 1),
                               __ATOMIC_RELEASE, __HIP_MEMORY_SCOPE_AGENT);
        if (tid < 64) {
            const unsigned tgt = (unsigned)(t0 + t + 1);
            for (;;) {
                unsigned f = __hip_atomic_load(&flags[tid], __ATOMIC_RELAXED,
                                               __HIP_MEMORY_SCOPE_AGENT);
                if (__all((int)(f >= tgt))) break;
                __builtin_amdgcn_s_sleep(1);
            }
            __builtin_amdgcn_fence(__ATOMIC_ACQUIRE, "agent");
        }
        __syncthreads();
        {
            const unsigned long long* row = (const unsigned long long*)(hist + (size_t)t * Hh);
            unsigned long long v = __hip_atomic_load(row + tid, __ATOMIC_RELAXED,
                                                     __HIP_MEMORY_SCOPE_AGENT);
            ((unsigned long long*)hl)[tid] = v;
        }
        __syncthreads();
    }
    if (wg == 0) {
        carry[tid] = hl[tid];
        carry[tid + NTH] = hl[tid + NTH];
        if (last) {
            outp[Hh + tid] = hl[tid];
            outp[Hh + tid + NTH] = hl[tid + NTH];
        }
    }
}

// ---------------------------------------------------------------- phase2: Gi1 = W_ih1 @ H0 + b_ih1
#define GM 64
#define GN 64
#define GK 32
__launch_bounds__(256)
__global__ void gemm1(const float* __restrict__ Wih1, const float* __restrict__ hist,
                      const float* __restrict__ bih1, float* __restrict__ gi1, int tc)
{
    __shared__ __align__(16) float As[GK][GM + 4];
    __shared__ __align__(16) float Bs[GK][GN + 4];
    const int tid = threadIdx.x;
    const int m0 = blockIdx.x * GM;
    const int n0 = blockIdx.y * GN;
    const int tx = tid & 15, ty = tid >> 4;
    float acc[4][4] = {};
    for (int k0 = 0; k0 < Hh; k0 += GK) {
        for (int i = tid; i < GM * GK; i += 256) {
            const int r = i >> 5, c = i & 31;
            As[c][r] = Wih1[(size_t)(m0 + r) * Hh + k0 + c];
        }
        for (int i = tid; i < GN * GK; i += 256) {
            const int r = i >> 5, c = i & 31;
            Bs[c][r] = (n0 + r < tc) ? hist[(size_t)(n0 + r) * Hh + k0 + c] : 0.f;
        }
        __syncthreads();
#pragma unroll
        for (int c = 0; c < GK; ++c) {
            const float4 av = *(const float4*)&As[c][tx * 4];
            const float4 bv = *(const float4*)&Bs[c][ty * 4];
            float a[4] = { av.x, av.y, av.z, av.w };
            float b[4] = { bv.x, bv.y, bv.z, bv.w };
#pragma unroll
            for (int ii = 0; ii < 4; ++ii)
#pragma unroll
                for (int jj = 0; jj < 4; ++jj)
                    acc[ii][jj] = fmaf(a[ii], b[jj], acc[ii][jj]);
        }
        __syncthreads();
    }
    const float4 bb = *(const float4*)&bih1[m0 + tx * 4];
#pragma unroll
    for (int j = 0; j < 4; ++j) {
        const int n = n0 + ty * 4 + j;
        if (n < tc) {
            float4 v = make_float4(acc[0][j] + bb.x, acc[1][j] + bb.y,
                                   acc[2][j] + bb.z, acc[3][j] + bb.w);
            *(float4*)&gi1[(size_t)n * TH + m0 + tx * 4] = v;
        }
    }
}

// ---------------------------------------------------------------- phase3: cell-1 serial scan + residual
__launch_bounds__(NTH, 1)
__global__ void phase3(const float* __restrict__ mem1, const float* __restrict__ resid,
                       const float* __restrict__ Whh1, const float* __restrict__ bhh1,
                       const float* __restrict__ gi1, float* __restrict__ h1pp,
                       float* __restrict__ carryh, float* __restrict__ carryr,
                       float* __restrict__ outp, unsigned* __restrict__ flags,
                       int t0, int tc, int first, int last)
{
    __shared__ __align__(16) float Wl[ROWS * Hh];
    __shared__ __align__(16) float hl[Hh];
    __shared__ float resl[JPW];
    const int tid = threadIdx.x;
    const int wg  = blockIdx.x;
    const int jl  = tid >> 5;
    const int s   = tid & 31;
    const int jg  = wg * JPW + jl;

    for (int i = tid; i < ROWS * Hh; i += NTH) {
        int lr = i >> 9, k = i & (Hh - 1);
        int g = lr % 3, j = lr / 3;
        int grow = g * Hh + wg * JPW + j;
        Wl[i] = Whh1[(size_t)grow * Hh + k];
    }
    {
        const float* src = first ? mem1 : carryh;
        hl[tid] = src[tid];
        hl[tid + NTH] = src[tid + NTH];
    }
    if (tid < JPW) resl[tid] = first ? resid[wg * JPW + tid] : carryr[wg * JPW + tid];
    const float Br = bhh1[jg], Bz = bhh1[jg + Hh], Bn2 = bhh1[jg + 2 * Hh];
    const float* Wr = &Wl[(jl * 3 + 0) * Hh];
    const float* Wz = &Wl[(jl * 3 + 1) * Hh];
    const float* Wn = &Wl[(jl * 3 + 2) * Hh];
    __syncthreads();

    for (int t = 0; t < tc; ++t) {
        float gr = 0.f, gz = 0.f, gn = 0.f;
        if (s == 0) {
            const float* g = &gi1[(size_t)t * TH];
            gr = g[jg]; gz = g[jg + Hh]; gn = g[jg + 2 * Hh];
        }
        float ar = 0.f, az = 0.f, an = 0.f;
#pragma unroll
        for (int i = 0; i < Hh / 32; ++i) {
            const int k = s + 32 * i;
            const float hk = hl[k];
            ar = fmaf(Wr[k], hk, ar);
            az = fmaf(Wz[k], hk, az);
            an = fmaf(Wn[k], hk, an);
        }
#pragma unroll
        for (int o = 16; o > 0; o >>= 1) {
            ar += __shfl_xor(ar, o);
            az += __shfl_xor(az, o);
            an += __shfl_xor(an, o);
        }
        if (s == 0) {
            const float r  = sigm(gr + Br + ar);
            const float z  = sigm(gz + Bz + az);
            const float n  = tanh_fast(gn + r * (an + Bn2));
            const float hn = (1.f - z) * n + z * hl[jg];
            __hip_atomic_store(&h1pp[(size_t)(t & 1) * Hh + jg], hn,
                               __ATOMIC_RELAXED, __HIP_MEMORY_SCOPE_AGENT);
            resl[jl] = sigm(resl[jl] + hn);
        }
        __syncthreads();
        if (tid == 0)
            __hip_atomic_store(&flags[wg], (unsigned)(t0 + t + 1),
                               __ATOMIC_RELEASE, __HIP_MEMORY_SCOPE_AGENT);
        if (tid < 64) {
            const unsigned tgt = (unsigned)(t0 + t + 1);
            for (;;) {
                unsigned f = __hip_atomic_load(&flags[tid], __ATOMIC_RELAXED,
                                               __HIP_MEMORY_SCOPE_AGENT);
                if (__all((int)(f >= tgt))) break;
                __builtin_amdgcn_s_sleep(1);
            }
            __builtin_amdgcn_fence(__ATOMIC_ACQUIRE, "agent");
        }
        __syncthreads();
        {
            const unsigned long long* row = (const unsigned long long*)(h1pp + (size_t)(t & 1) * Hh);
            unsigned long long v = __hip_atomic_load(row + tid, __ATOMIC_RELAXED,
                                                     __HIP_MEMORY_SCOPE_AGENT);
            ((unsigned long long*)hl)[tid] = v;
        }
        __syncthreads();
    }
    if (wg == 0) {
        carryh[tid] = hl[tid];
        carryh[tid + NTH] = hl[tid + NTH];
        if (last) {
            outp[2 * Hh + tid] = hl[tid];
            outp[2 * Hh + tid + NTH] = hl[tid + NTH];
        }
    }
    if (tid < JPW) {
        carryr[wg * JPW + tid] = resl[tid];
        if (last) outp[wg * JPW + tid] = resl[tid];
    }
}

// ---------------------------------------------------------------- host
extern "C" void kernel_launch(void* const* d_in, const int* in_sizes, int n_in,
                              void* d_out, int out_size, void* d_ws, size_t ws_size,
                              hipStream_t stream)
{
    const float* input    = (const float*)d_in[0];
    const float* residual = (const float*)d_in[1];
    const float* memory   = (const float*)d_in[2];
    const float* Wproc    = (const float*)d_in[3];
    const float* bproc    = (const float*)d_in[4];
    const float* Wih0     = (const float*)d_in[5];
    const float* Whh0     = (const float*)d_in[6];
    const float* bih0     = (const float*)d_in[7];
    const float* bhh0     = (const float*)d_in[8];
    const float* Wih1     = (const float*)d_in[9];
    const float* Whh1     = (const float*)d_in[10];
    const float* bih1     = (const float*)d_in[11];
    const float* bhh1     = (const float*)d_in[12];
    const int L = in_sizes[0];
    const int T = L - 1;
    float* out = (float*)d_out;
    char* ws = (char*)d_ws;

    float* A     = (float*)(ws + WS_A);
    float* CC    = (float*)(ws + WS_CC);
    float* ch0   = (float*)(ws + WS_CH0);
    float* ch1   = (float*)(ws + WS_CH1);
    float* cres  = (float*)(ws + WS_CRES);
    unsigned* f1 = (unsigned*)(ws + WS_FLAGS1);
    unsigned* f3 = (unsigned*)(ws + WS_FLAGS3);
    float* h1pp  = (float*)(ws + WS_H1PP);
    float* hist  = (float*)(ws + WS_HIST);

    long long avail = (long long)ws_size - WS_HIST;
    int tcmax = (int)(avail / ((Hh + TH) * 4));
    if (tcmax < 1) tcmax = 1;
    if (tcmax > T) tcmax = T;
    float* gi1 = (float*)(ws + WS_HIST + (size_t)tcmax * Hh * 4);

    hipMemsetAsync(ws + WS_FLAGS1, 0, 1024, stream);
    prep<<<dim3((TH + 255) / 256), dim3(256), 0, stream>>>(Wih0, Wproc, bproc, bih0, bhh0, A, CC);

    int t0 = 0;
    while (t0 < T) {
        int tc = T - t0; if (tc > tcmax) tc = tcmax;
        int first = (t0 == 0), last = (t0 + tc == T);
        phase1<<<dim3(NWG), dim3(NTH), 0, stream>>>(input, memory, Whh0, bhh0, A, CC,
                                                    hist, ch0, out, f1, t0, tc, first, last);
        dim3 gg(TH / GM, (tc + GN - 1) / GN);
        gemm1<<<gg, dim3(256), 0, stream>>>(Wih1, hist, bih1, gi1, tc);
        phase3<<<dim3(NWG), dim3(NTH), 0, stream>>>(memory + Hh, residual, Whh1, bhh1,
                                                    gi1, h1pp, ch1, cres, out, f3, t0, tc, first, last);
        t0 += tc;
    }
}

// Round 2
// 63506.903 us; speedup vs baseline: 1.1912x; 1.1912x over previous
//
#include <hip/hip_runtime.h>
#include <math.h>

#define Hh   512
#define TH   1536
#define LINN 128
#define NWG  64
#define NTH  256
#define JPW  (Hh / NWG)   /* 8 h-indices per WG  */
#define ROWS (3 * JPW)    /* 24 weight rows per WG */

#define WS_A      0
#define WS_CC     6144
#define WS_CH0    12288
#define WS_CH1    14336
#define WS_CRES   16384
#define WS_FLAGS1 18432
#define WS_FLAGS3 18944
#define WS_H1PP   20480
#define WS_HIST   32768

__device__ __forceinline__ float sigm(float v) { return 1.f / (1.f + __expf(-v)); }
__device__ __forceinline__ float tanh_fast(float x) { return 2.f / (1.f + __expf(-2.f * x)) - 1.f; }

// ---------------------------------------------------------------- prep:
// A[row] = W_ih0[row,:] @ W_proc ; CC[row] = W_ih0[row,:] @ b_proc + b_ih0 (+ b_hh0 for r,z rows)
__global__ void prep(const float* __restrict__ Wih0, const float* __restrict__ Wproc,
                     const float* __restrict__ bproc, const float* __restrict__ bih0,
                     const float* __restrict__ bhh0, float* __restrict__ A,
                     float* __restrict__ CC)
{
    int row = blockIdx.x * 256 + threadIdx.x;
    if (row >= TH) return;
    const float* w = Wih0 + (size_t)row * LINN;
    float a = 0.f, c = 0.f;
    for (int k = 0; k < LINN; ++k) { float wv = w[k]; a = fmaf(wv, Wproc[k], a); c = fmaf(wv, bproc[k], c); }
    c += bih0[row];
    if (row < 2 * Hh) c += bhh0[row];
    A[row] = a; CC[row] = c;
}

// ---------------------------------------------------------------- phase1: cell-0 serial scan
__launch_bounds__(NTH, 1)
__global__ void phase1(const float* __restrict__ input, const float* __restrict__ mem0,
                       const float* __restrict__ Whh0, const float* __restrict__ bhh0,
                       const float* __restrict__ A, const float* __restrict__ CC,
                       float* __restrict__ hist, float* __restrict__ carry,
                       float* __restrict__ outp, unsigned* __restrict__ flags,
                       int t0, int tc, int first, int last)
{
    __shared__ __align__(16) float Wl[ROWS * Hh];   // 48 KB weight slice
    __shared__ __align__(16) float hl[Hh];
    const int tid = threadIdx.x;
    const int wg  = blockIdx.x;
    const int jl  = tid >> 5;        // 0..7   local h-index
    const int s   = tid & 31;        // 0..31  k-stripe lane
    const int jg  = wg * JPW + jl;   // global h-index

    for (int i = tid; i < ROWS * Hh; i += NTH) {
        int lr = i >> 9, k = i & (Hh - 1);
        int g = lr % 3, j = lr / 3;
        int grow = g * Hh + wg * JPW + j;
        Wl[i] = Whh0[(size_t)grow * Hh + k];
    }
    {
        const float* src = first ? mem0 : carry;
        hl[tid] = src[tid];
        hl[tid + NTH] = src[tid + NTH];
    }
    const float Ar = A[jg], Az = A[jg + Hh], An = A[jg + 2 * Hh];
    const float Cr = CC[jg], Cz = CC[jg + Hh], Cn = CC[jg + 2 * Hh];
    const float Bn = bhh0[jg + 2 * Hh];
    const float* Wr = &Wl[(jl * 3 + 0) * Hh];
    const float* Wz = &Wl[(jl * 3 + 1) * Hh];
    const float* Wn = &Wl[(jl * 3 + 2) * Hh];
    __syncthreads();

    for (int t = 0; t < tc; ++t) {
        const float x = input[t0 + t];
        float ar = 0.f, az = 0.f, an = 0.f;
#pragma unroll
        for (int i = 0; i < Hh / 32; ++i) {
            const int k = s + 32 * i;
            const float hk = hl[k];
            ar = fmaf(Wr[k], hk, ar);
            az = fmaf(Wz[k], hk, az);
            an = fmaf(Wn[k], hk, an);
        }
#pragma unroll
        for (int o = 16; o > 0; o >>= 1) {
            ar += __shfl_xor(ar, o);
            az += __shfl_xor(az, o);
            an += __shfl_xor(an, o);
        }
        if (s == 0) {
            const float r  = sigm(fmaf(Ar, x, Cr) + ar);
            const float z  = sigm(fmaf(Az, x, Cz) + az);
            const float n  = tanh_fast(fmaf(An, x, Cn) + r * (an + Bn));
            const float hn = (1.f - z) * n + z * hl[jg];
            __hip_atomic_store(&hist[(size_t)t * Hh + jg], hn,
                               __ATOMIC_RELAXED, __HIP_MEMORY_SCOPE_AGENT);
        }
        __syncthreads();                     // compiler drains vmcnt(0) before s_barrier
        if (tid == 0) {
            asm volatile("s_waitcnt vmcnt(0)" ::: "memory");   // belt-and-braces: hn stores at LLC
            __hip_atomic_store(&flags[wg], (unsigned)(t0 + t + 1),
                               __ATOMIC_RELAXED, __HIP_MEMORY_SCOPE_AGENT);
        }
        if (tid < 64) {
            const unsigned tgt = (unsigned)(t0 + t + 1);
            for (;;) {
                unsigned f = __hip_atomic_load(&flags[tid], __ATOMIC_RELAXED,
                                               __HIP_MEMORY_SCOPE_AGENT);
                if (__all((int)(f >= tgt))) break;
                __builtin_amdgcn_s_sleep(1);
            }
            // no acquire fence: hist exchange uses cache-bypassing (agent-scope) atomics,
            // and per-wave in-order VMEM issue + the control dependency on the flag load
            // orders the hist loads after flag observation.
        }
        __syncthreads();
        {
            const unsigned long long* row = (const unsigned long long*)(hist + (size_t)t * Hh);
            unsigned long long v = __hip_atomic_load(row + tid, __ATOMIC_RELAXED,
                                                     __HIP_MEMORY_SCOPE_AGENT);
            ((unsigned long long*)hl)[tid] = v;
        }
        __syncthreads();
    }
    if (wg == 0) {
        carry[tid] = hl[tid];
        carry[tid + NTH] = hl[tid + NTH];
        if (last) {
            outp[Hh + tid] = hl[tid];
            outp[Hh + tid + NTH] = hl[tid + NTH];
        }
    }
}

// ---------------------------------------------------------------- phase2: Gi1 = W_ih1 @ H0 + b_ih1
#define GM 64
#define GN 64
#define GK 32
__launch_bounds__(256)
__global__ void gemm1(const float* __restrict__ Wih1, const float* __restrict__ hist,
                      const float* __restrict__ bih1, float* __restrict__ gi1, int tc)
{
    __shared__ __align__(16) float As[GK][GM + 4];
    __shared__ __align__(16) float Bs[GK][GN + 4];
    const int tid = threadIdx.x;
    const int m0 = blockIdx.x * GM;
    const int n0 = blockIdx.y * GN;
    const int tx = tid & 15, ty = tid >> 4;
    float acc[4][4] = {};
    for (int k0 = 0; k0 < Hh; k0 += GK) {
        for (int i = tid; i < GM * GK; i += 256) {
            const int r = i >> 5, c = i & 31;
            As[c][r] = Wih1[(size_t)(m0 + r) * Hh + k0 + c];
        }
        for (int i = tid; i < GN * GK; i += 256) {
            const int r = i >> 5, c = i & 31;
            Bs[c][r] = (n0 + r < tc) ? hist[(size_t)(n0 + r) * Hh + k0 + c] : 0.f;
        }
        __syncthreads();
#pragma unroll
        for (int c = 0; c < GK; ++c) {
            const float4 av = *(const float4*)&As[c][tx * 4];
            const float4 bv = *(const float4*)&Bs[c][ty * 4];
            float a[4] = { av.x, av.y, av.z, av.w };
            float b[4] = { bv.x, bv.y, bv.z, bv.w };
#pragma unroll
            for (int ii = 0; ii < 4; ++ii)
#pragma unroll
                for (int jj = 0; jj < 4; ++jj)
                    acc[ii][jj] = fmaf(a[ii], b[jj], acc[ii][jj]);
        }
        __syncthreads();
    }
    const float4 bb = *(const float4*)&bih1[m0 + tx * 4];
#pragma unroll
    for (int j = 0; j < 4; ++j) {
        const int n = n0 + ty * 4 + j;
        if (n < tc) {
            float4 v = make_float4(acc[0][j] + bb.x, acc[1][j] + bb.y,
                                   acc[2][j] + bb.z, acc[3][j] + bb.w);
            *(float4*)&gi1[(size_t)n * TH + m0 + tx * 4] = v;
        }
    }
}

// ---------------------------------------------------------------- phase3: cell-1 serial scan + residual
__launch_bounds__(NTH, 1)
__global__ void phase3(const float* __restrict__ mem1, const float* __restrict__ resid,
                       const float* __restrict__ Whh1, const float* __restrict__ bhh1,
                       const float* __restrict__ gi1, float* __restrict__ h1pp,
                       float* __restrict__ carryh, float* __restrict__ carryr,
                       float* __restrict__ outp, unsigned* __restrict__ flags,
                       int t0, int tc, int first, int last)
{
    __shared__ __align__(16) float Wl[ROWS * Hh];
    __shared__ __align__(16) float hl[Hh];
    __shared__ float resl[JPW];
    const int tid = threadIdx.x;
    const int wg  = blockIdx.x;
    const int jl  = tid >> 5;
    const int s   = tid & 31;
    const int jg  = wg * JPW + jl;

    for (int i = tid; i < ROWS * Hh; i += NTH) {
        int lr = i >> 9, k = i & (Hh - 1);
        int g = lr % 3, j = lr / 3;
        int grow = g * Hh + wg * JPW + j;
        Wl[i] = Whh1[(size_t)grow * Hh + k];
    }
    {
        const float* src = first ? mem1 : carryh;
        hl[tid] = src[tid];
        hl[tid + NTH] = src[tid + NTH];
    }
    if (tid < JPW) resl[tid] = first ? resid[wg * JPW + tid] : carryr[wg * JPW + tid];
    const float Br = bhh1[jg], Bz = bhh1[jg + Hh], Bn2 = bhh1[jg + 2 * Hh];
    const float* Wr = &Wl[(jl * 3 + 0) * Hh];
    const float* Wz = &Wl[(jl * 3 + 1) * Hh];
    const float* Wn = &Wl[(jl * 3 + 2) * Hh];
    __syncthreads();

    for (int t = 0; t < tc; ++t) {
        float gr = 0.f, gz = 0.f, gn = 0.f;
        if (s == 0) {
            const float* g = &gi1[(size_t)t * TH];
            gr = g[jg]; gz = g[jg + Hh]; gn = g[jg + 2 * Hh];
        }
        float ar = 0.f, az = 0.f, an = 0.f;
#pragma unroll
        for (int i = 0; i < Hh / 32; ++i) {
            const int k = s + 32 * i;
            const float hk = hl[k];
            ar = fmaf(Wr[k], hk, ar);
            az = fmaf(Wz[k], hk, az);
            an = fmaf(Wn[k], hk, an);
        }
#pragma unroll
        for (int o = 16; o > 0; o >>= 1) {
            ar += __shfl_xor(ar, o);
            az += __shfl_xor(az, o);
            an += __shfl_xor(an, o);
        }
        if (s == 0) {
            const float r  = sigm(gr + Br + ar);
            const float z  = sigm(gz + Bz + az);
            const float n  = tanh_fast(gn + r * (an + Bn2));
            const float hn = (1.f - z) * n + z * hl[jg];
            __hip_atomic_store(&h1pp[(size_t)(t & 1) * Hh + jg], hn,
                               __ATOMIC_RELAXED, __HIP_MEMORY_SCOPE_AGENT);
            resl[jl] = sigm(resl[jl] + hn);
        }
        __syncthreads();                     // compiler drains vmcnt(0) before s_barrier
        if (tid == 0) {
            asm volatile("s_waitcnt vmcnt(0)" ::: "memory");
            __hip_atomic_store(&flags[wg], (unsigned)(t0 + t + 1),
                               __ATOMIC_RELAXED, __HIP_MEMORY_SCOPE_AGENT);
        }
        if (tid < 64) {
            const unsigned tgt = (unsigned)(t0 + t + 1);
            for (;;) {
                unsigned f = __hip_atomic_load(&flags[tid], __ATOMIC_RELAXED,
                                               __HIP_MEMORY_SCOPE_AGENT);
                if (__all((int)(f >= tgt))) break;
                __builtin_amdgcn_s_sleep(1);
            }
        }
        __syncthreads();
        {
            const unsigned long long* row = (const unsigned long long*)(h1pp + (size_t)(t & 1) * Hh);
            unsigned long long v = __hip_atomic_load(row + tid, __ATOMIC_RELAXED,
                                                     __HIP_MEMORY_SCOPE_AGENT);
            ((unsigned long long*)hl)[tid] = v;
        }
        __syncthreads();
    }
    if (wg == 0) {
        carryh[tid] = hl[tid];
        carryh[tid + NTH] = hl[tid + NTH];
        if (last) {
            outp[2 * Hh + tid] = hl[tid];
            outp[2 * Hh + tid + NTH] = hl[tid + NTH];
        }
    }
    if (tid < JPW) {
        carryr[wg * JPW + tid] = resl[tid];
        if (last) outp[wg * JPW + tid] = resl[tid];
    }
}

// ---------------------------------------------------------------- host
extern "C" void kernel_launch(void* const* d_in, const int* in_sizes, int n_in,
                              void* d_out, int out_size, void* d_ws, size_t ws_size,
                              hipStream_t stream)
{
    const float* input    = (const float*)d_in[0];
    const float* residual = (const float*)d_in[1];
    const float* memory   = (const float*)d_in[2];
    const float* Wproc    = (const float*)d_in[3];
    const float* bproc    = (const float*)d_in[4];
    const float* Wih0     = (const float*)d_in[5];
    const float* Whh0     = (const float*)d_in[6];
    const float* bih0     = (const float*)d_in[7];
    const float* bhh0     = (const float*)d_in[8];
    const float* Wih1     = (const float*)d_in[9];
    const float* Whh1     = (const float*)d_in[10];
    const float* bih1     = (const float*)d_in[11];
    const float* bhh1     = (const float*)d_in[12];
    const int L = in_sizes[0];
    const int T = L - 1;
    float* out = (float*)d_out;
    char* ws = (char*)d_ws;

    float* A     = (float*)(ws + WS_A);
    float* CC    = (float*)(ws + WS_CC);
    float* ch0   = (float*)(ws + WS_CH0);
    float* ch1   = (float*)(ws + WS_CH1);
    float* cres  = (float*)(ws + WS_CRES);
    unsigned* f1 = (unsigned*)(ws + WS_FLAGS1);
    unsigned* f3 = (unsigned*)(ws + WS_FLAGS3);
    float* h1pp  = (float*)(ws + WS_H1PP);
    float* hist  = (float*)(ws + WS_HIST);

    long long avail = (long long)ws_size - WS_HIST;
    int tcmax = (int)(avail / ((Hh + TH) * 4));
    if (tcmax < 1) tcmax = 1;
    if (tcmax > T) tcmax = T;
    float* gi1 = (float*)(ws + WS_HIST + (size_t)tcmax * Hh * 4);

    hipMemsetAsync(ws + WS_FLAGS1, 0, 1024, stream);
    prep<<<dim3((TH + 255) / 256), dim3(256), 0, stream>>>(Wih0, Wproc, bproc, bih0, bhh0, A, CC);

    int t0 = 0;
    while (t0 < T) {
        int tc = T - t0; if (tc > tcmax) tc = tcmax;
        int first = (t0 == 0), last = (t0 + tc == T);
        phase1<<<dim3(NWG), dim3(NTH), 0, stream>>>(input, memory, Whh0, bhh0, A, CC,
                                                    hist, ch0, out, f1, t0, tc, first, last);
        dim3 gg(TH / GM, (tc + GN - 1) / GN);
        gemm1<<<gg, dim3(256), 0, stream>>>(Wih1, hist, bih1, gi1, tc);
        phase3<<<dim3(NWG), dim3(NTH), 0, stream>>>(memory + Hh, residual, Whh1, bhh1,
                                                    gi1, h1pp, ch1, cres, out, f3, t0, tc, first, last);
        t0 += tc;
    }
}

// Round 3
// 20032.970 us; speedup vs baseline: 3.7762x; 3.1701x over previous
//
#include <hip/hip_runtime.h>
#include <math.h>

#define Hh   512
#define TH   1536
#define LINN 128
typedef unsigned long long ull;
typedef unsigned int u32;

#define WS_A     0
#define WS_CC    6144
#define WS_RING0 16384
#define WS_RING1 49152
// ws usage ends at 81920 bytes

__device__ __forceinline__ float sigm(float v) { return 1.f / (1.f + __expf(-v)); }
__device__ __forceinline__ float tanh_fast(float x) { return 2.f / (1.f + __expf(-2.f * x)) - 1.f; }
__device__ __forceinline__ ull  pk(float v, u32 tag) { return ((ull)tag << 32) | (ull)__float_as_uint(v); }
__device__ __forceinline__ ull  ring_ld(const ull* p) {
    return __hip_atomic_load(p, __ATOMIC_RELAXED, __HIP_MEMORY_SCOPE_AGENT);
}
__device__ __forceinline__ void ring_st(ull* p, ull v) {
    __hip_atomic_store(p, v, __ATOMIC_RELAXED, __HIP_MEMORY_SCOPE_AGENT);
}

// ---------------------------------------------------------------- prep:
// A[row] = W_ih0[row,:]@W_proc ; CC[row] = W_ih0[row,:]@b_proc + b_ih0 (+ b_hh0 for r,z rows)
__global__ void prep(const float* __restrict__ Wih0, const float* __restrict__ Wproc,
                     const float* __restrict__ bproc, const float* __restrict__ bih0,
                     const float* __restrict__ bhh0, float* __restrict__ A,
                     float* __restrict__ CC)
{
    int row = blockIdx.x * 256 + threadIdx.x;
    if (row >= TH) return;
    const float* w = Wih0 + (size_t)row * LINN;
    float a = 0.f, c = 0.f;
    for (int k = 0; k < LINN; ++k) { float wv = w[k]; a = fmaf(wv, Wproc[k], a); c = fmaf(wv, bproc[k], c); }
    c += bih0[row];
    if (row < 2 * Hh) c += bhh0[row];
    A[row] = a; CC[row] = c;
}

// ---------------------------------------------------------------- ring init (tags + initial state, every call)
__global__ void ringinit(const float* __restrict__ mem, ull* __restrict__ ring0,
                         ull* __restrict__ ring1)
{
    const int t = threadIdx.x;          // 512 threads
    for (int slot = 0; slot < 8; ++slot) {
        ring0[slot * Hh + t] = pk(slot == 7 ? mem[t]      : 0.f, 0u);
        ring1[slot * Hh + t] = pk(slot == 7 ? mem[Hh + t] : 0.f, 0u);
    }
}

// ---------------------------------------------------------------- fused self-timed dataflow scan
// WG 0..63   : layer 0  (8 h-indices each; 24 rows of Whh0 in LDS)
// WG 64..191 : layer 1, 1-step lag (4 h-indices each; 24 row-equivalents of Wih1+Whh1 in LDS)
// Exchange: 8-deep rings of (float value | u32 tag) packed 8B words, relaxed agent atomics.
__launch_bounds__(256, 1)
__global__ void fused(const float* __restrict__ input, const float* __restrict__ resid,
                      const float* __restrict__ Whh0, const float* __restrict__ bhh0,
                      const float* __restrict__ A, const float* __restrict__ CC,
                      const float* __restrict__ Wih1, const float* __restrict__ Whh1,
                      const float* __restrict__ bih1, const float* __restrict__ bhh1,
                      ull* __restrict__ ring0, ull* __restrict__ ring1,
                      float* __restrict__ outp, int T)
{
    __shared__ __align__(16) float smem[13312];   // 53 KB: 24x512 weights + h buffers
    const int tid = threadIdx.x;
    const int wg  = blockIdx.x;

    if (wg < 64) {
        // ---------------- layer 0 ----------------
        float* Wl = smem;                  // [24][512]
        float* hl = smem + 12288;          // [512]
        const int jl = tid >> 5;           // 0..7
        const int s2 = tid & 31;
        const int jg = wg * 8 + jl;
        for (int i = tid; i < 24 * Hh; i += 256) {
            int lr = i >> 9, k = i & (Hh - 1);
            int g = lr % 3, j = lr / 3;
            Wl[i] = Whh0[(size_t)(g * Hh + wg * 8 + j) * Hh + k];
        }
        const float Ar = A[jg], Az = A[jg + Hh], An = A[jg + 2 * Hh];
        const float Cr = CC[jg], Cz = CC[jg + Hh], Cn = CC[jg + 2 * Hh];
        const float Bn = bhh0[jg + 2 * Hh];
        const float* Wr = &Wl[(jl * 3 + 0) * Hh];
        const float* Wz = &Wl[(jl * 3 + 1) * Hh];
        const float* Wn = &Wl[(jl * 3 + 2) * Hh];
        __syncthreads();

        for (int s = 0; s < T; ++s) {
            const ull* base = ring0 + ((s - 1) & 7) * Hh;
            const u32 tgt = (u32)s;
            ull w0, w1;
            do { w0 = ring_ld(base + tid);       } while ((u32)(w0 >> 32) < tgt);
            do { w1 = ring_ld(base + tid + 256); } while ((u32)(w1 >> 32) < tgt);
            if (tid == 0 && s >= 7) {            // back-pressure: layer1 past step s-8
                const ull* bp = ring1 + ((s - 7) & 7) * Hh;
                while ((u32)(ring_ld(bp) >> 32) < (u32)(s - 6)) {}
            }
            __syncthreads();                     // all polls done -> safe to overwrite hl
            hl[tid]       = __uint_as_float((u32)w0);
            hl[tid + 256] = __uint_as_float((u32)w1);
            __syncthreads();
            const float x = input[s];
            float ar = 0.f, az = 0.f, an = 0.f;
#pragma unroll
            for (int i = 0; i < 16; ++i) {
                int k = s2 + 32 * i;
                float hk = hl[k];
                ar = fmaf(Wr[k], hk, ar); az = fmaf(Wz[k], hk, az); an = fmaf(Wn[k], hk, an);
            }
#pragma unroll
            for (int o = 16; o > 0; o >>= 1) {
                ar += __shfl_xor(ar, o); az += __shfl_xor(az, o); an += __shfl_xor(an, o);
            }
            if (s2 == 0) {
                float r  = sigm(fmaf(Ar, x, Cr) + ar);
                float z  = sigm(fmaf(Az, x, Cz) + az);
                float n  = tanh_fast(fmaf(An, x, Cn) + r * (an + Bn));
                float hn = (1.f - z) * n + z * hl[jg];
                ring_st(ring0 + (s & 7) * Hh + jg, pk(hn, (u32)(s + 1)));
                if (s == T - 1) outp[Hh + jg] = hn;
            }
        }
    } else {
        // ---------------- layer 1 (lag 1) ----------------
        float* Wl  = smem;                 // [24][512]: per h: ihR,ihZ,ihN,hhR,hhZ,hhN
        float* hl0 = smem + 12288;         // [512]
        float* hl1 = smem + 12800;         // [512]
        const int w  = tid >> 6;           // wave 0..3
        const int l  = tid & 63;
        const int jg = (wg - 64) * 4 + w;
        for (int i = tid; i < 24 * Hh; i += 256) {
            int lr = i >> 9, k = i & (Hh - 1);
            int ww = lr / 6, q = lr % 6;
            int hj = (wg - 64) * 4 + ww;
            const float* src = (q < 3) ? &Wih1[(size_t)(q * Hh + hj) * Hh]
                                       : &Whh1[(size_t)((q - 3) * Hh + hj) * Hh];
            Wl[i] = src[k];
        }
        const float Br = bih1[jg] + bhh1[jg];
        const float Bz = bih1[jg + Hh] + bhh1[jg + Hh];
        const float Bin = bih1[jg + 2 * Hh];
        const float Bhn = bhh1[jg + 2 * Hh];
        const float* Xr = &Wl[(w * 6 + 0) * Hh];
        const float* Xz = &Wl[(w * 6 + 1) * Hh];
        const float* Xn = &Wl[(w * 6 + 2) * Hh];
        const float* Hr = &Wl[(w * 6 + 3) * Hh];
        const float* Hz = &Wl[(w * 6 + 4) * Hh];
        const float* Hn = &Wl[(w * 6 + 5) * Hh];
        float resl = resid[jg];            // live in lane 0
        __syncthreads();

        for (int u = 0; u < T; ++u) {
            const ull* b0 = ring0 + (u & 7) * Hh;          // h0[u], tag u+1
            const ull* b1 = ring1 + ((u - 1) & 7) * Hh;    // h1[u-1], tag u
            const u32 t0g = (u32)(u + 1), t1g = (u32)u;
            ull a0, a1, c0, c1;
            do { a0 = ring_ld(b0 + tid);       } while ((u32)(a0 >> 32) < t0g);
            do { a1 = ring_ld(b0 + tid + 256); } while ((u32)(a1 >> 32) < t0g);
            do { c0 = ring_ld(b1 + tid);       } while ((u32)(c0 >> 32) < t1g);
            do { c1 = ring_ld(b1 + tid + 256); } while ((u32)(c1 >> 32) < t1g);
            __syncthreads();                 // all polls done -> safe to overwrite hl0/hl1
            hl0[tid]       = __uint_as_float((u32)a0);
            hl0[tid + 256] = __uint_as_float((u32)a1);
            hl1[tid]       = __uint_as_float((u32)c0);
            hl1[tid + 256] = __uint_as_float((u32)c1);
            __syncthreads();
            float xr = 0.f, xz = 0.f, xn = 0.f, hr = 0.f, hz = 0.f, hq = 0.f;
#pragma unroll
            for (int i = 0; i < 8; ++i) {
                int k = l + 64 * i;
                float h0k = hl0[k], h1k = hl1[k];
                xr = fmaf(Xr[k], h0k, xr); xz = fmaf(Xz[k], h0k, xz); xn = fmaf(Xn[k], h0k, xn);
                hr = fmaf(Hr[k], h1k, hr); hz = fmaf(Hz[k], h1k, hz); hq = fmaf(Hn[k], h1k, hq);
            }
#pragma unroll
            for (int o = 32; o > 0; o >>= 1) {
                xr += __shfl_xor(xr, o); xz += __shfl_xor(xz, o); xn += __shfl_xor(xn, o);
                hr += __shfl_xor(hr, o); hz += __shfl_xor(hz, o); hq += __shfl_xor(hq, o);
            }
            if (l == 0) {
                float r   = sigm(xr + hr + Br);
                float z   = sigm(xz + hz + Bz);
                float n   = tanh_fast(xn + Bin + r * (hq + Bhn));
                float h1n = (1.f - z) * n + z * hl1[jg];
                ring_st(ring1 + (u & 7) * Hh + jg, pk(h1n, (u32)(u + 1)));
                resl = sigm(resl + h1n);
                if (u == T - 1) { outp[jg] = resl; outp[2 * Hh + jg] = h1n; }
            }
        }
    }
}

// ---------------------------------------------------------------- host
extern "C" void kernel_launch(void* const* d_in, const int* in_sizes, int n_in,
                              void* d_out, int out_size, void* d_ws, size_t ws_size,
                              hipStream_t stream)
{
    const float* input    = (const float*)d_in[0];
    const float* residual = (const float*)d_in[1];
    const float* memory   = (const float*)d_in[2];
    const float* Wproc    = (const float*)d_in[3];
    const float* bproc    = (const float*)d_in[4];
    const float* Wih0     = (const float*)d_in[5];
    const float* Whh0     = (const float*)d_in[6];
    const float* bih0     = (const float*)d_in[7];
    const float* bhh0     = (const float*)d_in[8];
    const float* Wih1     = (const float*)d_in[9];
    const float* Whh1     = (const float*)d_in[10];
    const float* bih1     = (const float*)d_in[11];
    const float* bhh1     = (const float*)d_in[12];
    const int L = in_sizes[0];
    const int T = L - 1;
    float* out = (float*)d_out;
    char* ws = (char*)d_ws;

    float* A     = (float*)(ws + WS_A);
    float* CC    = (float*)(ws + WS_CC);
    ull*   ring0 = (ull*)(ws + WS_RING0);
    ull*   ring1 = (ull*)(ws + WS_RING1);

    prep<<<dim3((TH + 255) / 256), dim3(256), 0, stream>>>(Wih0, Wproc, bproc, bih0, bhh0, A, CC);
    ringinit<<<dim3(1), dim3(512), 0, stream>>>(memory, ring0, ring1);
    fused<<<dim3(192), dim3(256), 0, stream>>>(input, residual, Whh0, bhh0, A, CC,
                                               Wih1, Whh1, bih1, bhh1,
                                               ring0, ring1, out, T);
}